// Round 11
// baseline (124.936 us; speedup 1.0000x reference)
//
#include <hip/hip_runtime.h>

#define NITER 12

typedef float v2f __attribute__((ext_vector_type(2)));

// R10 (passing, absmax 11.09375) restructured as persistent waves with 1-deep
// software prefetch. R9/R10 post-mortems: VALU count and DS-chain cuts were
// both neutral -> bottleneck is phase serialization (load burst -> register
// compute -> store, no memory/compute overlap across only 2 wave generations).
// Fix: 4096 waves (4/SIMD resident), each owning 4 batches of 4 rows; next
// batch's p_pred/total_load loads issue before the current batch's 12-iter
// compute (~1400 cyc >> ~900 cyc HBM latency) -> HBM fully overlapped.
// p_max is row-invariant -> loaded once per wave.
//
// Per-row math, lane mapping, and reduction tree are IDENTICAL to R10
// (bitwise-neutral; rows are independent, only wave->row scheduling changed):
//  - DPP row_ror 8/4/2/1 == R7's xor butterfly bitwise (period symmetry).
//  - v2f vertical packing preserves quad-sum association per component.
//  - p_min == 0; clip = med3; fma forms single-round where exact.
//  - FMA contraction off (g and lam + 0.8f*res round as separate ops).
__device__ __forceinline__ float dpp_ror_add(float x, const int ctrl_base) {
    int xi = __builtin_bit_cast(int, x);
    int yi;
    switch (ctrl_base) {
      case 8: yi = __builtin_amdgcn_update_dpp(0, xi, 0x128, 0xf, 0xf, true); break;
      case 4: yi = __builtin_amdgcn_update_dpp(0, xi, 0x124, 0xf, 0xf, true); break;
      case 2: yi = __builtin_amdgcn_update_dpp(0, xi, 0x122, 0xf, 0xf, true); break;
      default: yi = __builtin_amdgcn_update_dpp(0, xi, 0x121, 0xf, 0xf, true); break;
    }
    return x + __builtin_bit_cast(float, yi);
}

__global__ __launch_bounds__(256, 4) void dc_feas_kernel(
    const float* __restrict__ p_pred,
    const float* __restrict__ total_load,
    const float* __restrict__ p_min,
    const float* __restrict__ p_max,
    float* __restrict__ out, int B)
{
#pragma clang fp contract(off)
    const int lane = threadIdx.x & 63;
    const int wave = threadIdx.x >> 6;
    const int r    = lane >> 4;            // row within batch (0..3)
    const int t    = lane & 15;
    const int e0   = t << 2;

    const int w  = (blockIdx.x << 2) + wave;   // global wave id
    const int NW = gridDim.x << 2;             // total waves
    const int nbatch = (B + 3) >> 2;           // batches of 4 rows

    // p_max: row-invariant, load once per wave
    const float4 h0 = *(const float4*)(p_max + e0);
    const float4 h1 = *(const float4*)(p_max + e0 + 64);
    const float4 h2 = *(const float4*)(p_max + e0 + 128);
    const float4 h3 = *(const float4*)(p_max + e0 + 192);
    v2f HI[8];
    HI[0] = (v2f){h0.x, h2.x}; HI[1] = (v2f){h0.y, h2.y};
    HI[2] = (v2f){h0.z, h2.z}; HI[3] = (v2f){h0.w, h2.w};
    HI[4] = (v2f){h1.x, h3.x}; HI[5] = (v2f){h1.y, h3.y};
    HI[6] = (v2f){h1.z, h3.z}; HI[7] = (v2f){h1.w, h3.w};

    int bidx = w;
    if (bidx >= nbatch) return;

    auto rowsum = [&](const v2f* v) -> float {
        const v2f A  = (v[0] + v[1]) + (v[2] + v[3]);
        const v2f Bq = (v[4] + v[5]) + (v[6] + v[7]);
        float s = (A.x + A.y) + (Bq.x + Bq.y);   // (q0+q2)+(q1+q3)
        s = dpp_ror_add(s, 8);
        s = dpp_ror_add(s, 4);
        s = dpp_ror_add(s, 2);
        s = dpp_ror_add(s, 1);
        return s;
    };

    // load batch 0
    float4 c0, c1, c2, c3; float cload;
    {
        const size_t cb = (size_t)(bidx * 4 + r) * 256 + e0;
        c0 = *(const float4*)(p_pred + cb);
        c1 = *(const float4*)(p_pred + cb + 64);
        c2 = *(const float4*)(p_pred + cb + 128);
        c3 = *(const float4*)(p_pred + cb + 192);
        cload = total_load[bidx * 4 + r];
    }

    for (;;) {
        const int nxt = bidx + NW;
        const bool has_nxt = nxt < nbatch;     // wave-uniform
        float4 n0, n1, n2, n3; float nload;
        if (has_nxt) {                          // prefetch next batch
            const size_t nb = (size_t)(nxt * 4 + r) * 256 + e0;
            n0 = *(const float4*)(p_pred + nb);
            n1 = *(const float4*)(p_pred + nb + 64);
            n2 = *(const float4*)(p_pred + nb + 128);
            n3 = *(const float4*)(p_pred + nb + 192);
            nload = total_load[nxt * 4 + r];
        }

        // pack current batch
        v2f PR[8], P[8];
        PR[0] = (v2f){c0.x, c2.x}; PR[1] = (v2f){c0.y, c2.y};
        PR[2] = (v2f){c0.z, c2.z}; PR[3] = (v2f){c0.w, c2.w};
        PR[4] = (v2f){c1.x, c3.x}; PR[5] = (v2f){c1.y, c3.y};
        PR[6] = (v2f){c1.z, c3.z}; PR[7] = (v2f){c1.w, c3.w};
        const float load = cload;
        const size_t base = (size_t)(bidx * 4 + r) * 256;

        // ---- iter 0: p==pred, lam==0 -> p = clip(pred) exactly ----
#pragma unroll
        for (int j = 0; j < 8; ++j) {
            P[j].x = __builtin_amdgcn_fmed3f(PR[j].x, 0.0f, HI[j].x);
            P[j].y = __builtin_amdgcn_fmed3f(PR[j].y, 0.0f, HI[j].y);
        }
        float res = rowsum(P) - load;
        float lam = __builtin_amdgcn_fmed3f(0.8f * res, -1000000.0f, 1000000.0f);

        // ---- iters 1..11 ----
        for (int it = 1; it < NITER; ++it) {
            const v2f lam2  = (v2f){lam, lam};
            const v2f mhalf = (v2f){-0.5f, -0.5f};
#pragma unroll
            for (int j = 0; j < 8; ++j) {
                const v2f g  = (P[j] - PR[j]) + lam2;
                const v2f pn = __builtin_elementwise_fma(g, mhalf, P[j]);
                P[j].x = __builtin_amdgcn_fmed3f(pn.x, 0.0f, HI[j].x);
                P[j].y = __builtin_amdgcn_fmed3f(pn.y, 0.0f, HI[j].y);
            }
            res = rowsum(P) - load;
            const float dl = 0.8f * res;
            lam = __builtin_amdgcn_fmed3f(lam + dl, -1000000.0f, 1000000.0f);
        }

        v2f M[8];
#pragma unroll
        for (int j = 0; j < 8; ++j) {
            M[j].x = (P[j].x > 1e-8f && P[j].x < HI[j].x - 1e-8f) ? 1.0f : 0.0f;
            M[j].y = (P[j].y > 1e-8f && P[j].y < HI[j].y - 1e-8f) ? 1.0f : 0.0f;
        }
        float ss = rowsum(M);
        ss = (ss == 0.0f) ? 1.0f : ss;
        const float adj = res / ss;

        const v2f madj2 = (v2f){-adj, -adj};
        v2f O[8];
#pragma unroll
        for (int j = 0; j < 8; ++j)
            O[j] = __builtin_elementwise_fma(M[j], madj2, P[j]);

        float4 o;
        o.x = O[0].x; o.y = O[1].x; o.z = O[2].x; o.w = O[3].x;
        *(float4*)(out + base + e0) = o;
        o.x = O[4].x; o.y = O[5].x; o.z = O[6].x; o.w = O[7].x;
        *(float4*)(out + base + e0 + 64) = o;
        o.x = O[0].y; o.y = O[1].y; o.z = O[2].y; o.w = O[3].y;
        *(float4*)(out + base + e0 + 128) = o;
        o.x = O[4].y; o.y = O[5].y; o.z = O[6].y; o.w = O[7].y;
        *(float4*)(out + base + e0 + 192) = o;

        if (!has_nxt) break;
        c0 = n0; c1 = n1; c2 = n2; c3 = n3; cload = nload;
        bidx = nxt;
    }
}

extern "C" void kernel_launch(void* const* d_in, const int* in_sizes, int n_in,
                              void* d_out, int out_size, void* d_ws, size_t ws_size,
                              hipStream_t stream) {
    const float* p_pred     = (const float*)d_in[0];
    const float* total_load = (const float*)d_in[1];
    const float* p_min      = (const float*)d_in[2];
    const float* p_max      = (const float*)d_in[3];
    float* out = (float*)d_out;

    const int B = in_sizes[1];            // 65536
    // 1024 blocks x 4 waves = 4096 waves = 4 waves/SIMD resident (VGPR<=128
    // via __launch_bounds__(256,4)); each wave owns ceil(nbatch/4096) batches
    // of 4 rows with 1-deep prefetch.
    const int nbatch = (B + 3) >> 2;
    int grid = 1024;
    if (grid > nbatch) grid = (nbatch + 3) >> 2 ? (nbatch + 3) >> 2 : 1;

    dc_feas_kernel<<<grid, 256, 0, stream>>>(p_pred, total_load, p_min, p_max, out, B);
}

// Round 12
// 121.154 us; speedup vs baseline: 1.0312x; 1.0312x over previous
//
#include <hip/hip_runtime.h>

#define NITER 12

typedef float v2f __attribute__((ext_vector_type(2)));

// Max-occupancy variant. R9 (-VALU) and R10 (-DS) were neutral; R11 (fewer
// waves) regressed -> kernel is latency-bound, hidden by TLP only. This
// round: 2 rows/wave (32 lanes/row), register state 24 VGPRs (was 48), with
// __launch_bounds__(256,8) forcing VGPR<=64 -> 8 waves/SIMD resident (2x R10),
// 32768 waves total, plain grid (no persistence, no prefetch).
//
// Bitwise-exact vs R7's passing tree (absmax must stay 11.09375):
//  - lane t holds quads t and t+32 (elems 4t..4t+3 and 4t+128..4t+131);
//    v2f pair j = (elem 4t+j, elem 4t+128+j); quad association
//    (e0+e1)+(e2+e3) preserved per component; A.x+A.y == q_t + q_{t+32}
//    == R7's xor-32 butterfly step (same operands, same order).
//  - then shfl_xor 16 (exact lane t^16), then DPP row_ror 8/4/2/1 within
//    16-lane rows == xor 8/4/2/1 (period-symmetry argument, R10-verified).
//  - p_min == 0: clip = med3(pn, 0, hi); mask lower test p > 1e-8f.
//  - fma(-0.5,g,p) == p - 0.5f*g (0.5*g exact); fma(m,-adj,p) == p - adj*m.
//  - FMA contraction off (g and lam + 0.8f*res round as separate ops).
__device__ __forceinline__ float dpp_ror_add(float x, const int ctrl_base) {
    int xi = __builtin_bit_cast(int, x);
    int yi;
    switch (ctrl_base) {
      case 8: yi = __builtin_amdgcn_update_dpp(0, xi, 0x128, 0xf, 0xf, true); break;
      case 4: yi = __builtin_amdgcn_update_dpp(0, xi, 0x124, 0xf, 0xf, true); break;
      case 2: yi = __builtin_amdgcn_update_dpp(0, xi, 0x122, 0xf, 0xf, true); break;
      default: yi = __builtin_amdgcn_update_dpp(0, xi, 0x121, 0xf, 0xf, true); break;
    }
    return x + __builtin_bit_cast(float, yi);
}

__global__ __launch_bounds__(256, 8) void dc_feas_kernel(
    const float* __restrict__ p_pred,
    const float* __restrict__ total_load,
    const float* __restrict__ p_min,
    const float* __restrict__ p_max,
    float* __restrict__ out, int B)
{
#pragma clang fp contract(off)
    const int lane = threadIdx.x & 63;
    const int wave = threadIdx.x >> 6;
    const int r    = lane >> 5;          // row within wave (0..1)
    const int t    = lane & 31;

    const int row = (blockIdx.x << 3) + (wave << 1) + r;
    if (row >= B) return;

    const size_t base = (size_t)row * 256;
    const int e0 = t << 2;

    const float4 a0 = *(const float4*)(p_pred + base + e0);        // quad t
    const float4 a1 = *(const float4*)(p_pred + base + e0 + 128);  // quad t+32
    const float4 h0 = *(const float4*)(p_max + e0);
    const float4 h1 = *(const float4*)(p_max + e0 + 128);

    v2f PR[4], HI[4], P[4];
    PR[0] = (v2f){a0.x, a1.x}; PR[1] = (v2f){a0.y, a1.y};
    PR[2] = (v2f){a0.z, a1.z}; PR[3] = (v2f){a0.w, a1.w};
    HI[0] = (v2f){h0.x, h1.x}; HI[1] = (v2f){h0.y, h1.y};
    HI[2] = (v2f){h0.z, h1.z}; HI[3] = (v2f){h0.w, h1.w};

    const float load = total_load[row];

    auto rowsum = [&](const v2f* v) -> float {
        const v2f A = (v[0] + v[1]) + (v[2] + v[3]);  // (q_t, q_{t+32})
        float s = A.x + A.y;                          // == R7 xor-32 step
        s += __shfl_xor(s, 16, 64);                   // exact lane t^16
        s = dpp_ror_add(s, 8);                        // == xor 8 (symmetry)
        s = dpp_ror_add(s, 4);
        s = dpp_ror_add(s, 2);
        s = dpp_ror_add(s, 1);
        return s;
    };

    // ---- iter 0: p==pred, lam==0 -> p = clip(pred) exactly ----
#pragma unroll
    for (int j = 0; j < 4; ++j) {
        P[j].x = __builtin_amdgcn_fmed3f(PR[j].x, 0.0f, HI[j].x);
        P[j].y = __builtin_amdgcn_fmed3f(PR[j].y, 0.0f, HI[j].y);
    }
    float res = rowsum(P) - load;
    float lam = __builtin_amdgcn_fmed3f(0.8f * res, -1000000.0f, 1000000.0f);

    // ---- iters 1..11 ----
    for (int it = 1; it < NITER; ++it) {
        const v2f lam2  = (v2f){lam, lam};
        const v2f mhalf = (v2f){-0.5f, -0.5f};
#pragma unroll
        for (int j = 0; j < 4; ++j) {
            const v2f g  = (P[j] - PR[j]) + lam2;
            const v2f pn = __builtin_elementwise_fma(g, mhalf, P[j]); // == p-0.5f*g
            P[j].x = __builtin_amdgcn_fmed3f(pn.x, 0.0f, HI[j].x);
            P[j].y = __builtin_amdgcn_fmed3f(pn.y, 0.0f, HI[j].y);
        }
        res = rowsum(P) - load;
        const float dl = 0.8f * res;              // separate mul
        lam = __builtin_amdgcn_fmed3f(lam + dl, -1000000.0f, 1000000.0f);
    }
    // final res == last iteration's res bitwise (p unchanged since)

    v2f M[4];
#pragma unroll
    for (int j = 0; j < 4; ++j) {
        M[j].x = (P[j].x > 1e-8f && P[j].x < HI[j].x - 1e-8f) ? 1.0f : 0.0f;
        M[j].y = (P[j].y > 1e-8f && P[j].y < HI[j].y - 1e-8f) ? 1.0f : 0.0f;
    }
    float ss = rowsum(M);                         // exact small ints: order-free
    ss = (ss == 0.0f) ? 1.0f : ss;
    const float adj = res / ss;                   // IEEE f32 div, uniform per row

    const v2f madj2 = (v2f){-adj, -adj};
    v2f O[4];
#pragma unroll
    for (int j = 0; j < 4; ++j)                   // p - adj*m (adj*m exact)
        O[j] = __builtin_elementwise_fma(M[j], madj2, P[j]);

    float4 o;
    o.x = O[0].x; o.y = O[1].x; o.z = O[2].x; o.w = O[3].x;
    *(float4*)(out + base + e0) = o;
    o.x = O[0].y; o.y = O[1].y; o.z = O[2].y; o.w = O[3].y;
    *(float4*)(out + base + e0 + 128) = o;
}

extern "C" void kernel_launch(void* const* d_in, const int* in_sizes, int n_in,
                              void* d_out, int out_size, void* d_ws, size_t ws_size,
                              hipStream_t stream) {
    const float* p_pred     = (const float*)d_in[0];
    const float* total_load = (const float*)d_in[1];
    const float* p_min      = (const float*)d_in[2];
    const float* p_max      = (const float*)d_in[3];
    float* out = (float*)d_out;

    const int B = in_sizes[1];            // 65536
    const int rows_per_block = 8;         // 4 waves x 2 rows/wave
    const int grid = (B + rows_per_block - 1) / rows_per_block;

    dc_feas_kernel<<<grid, 256, 0, stream>>>(p_pred, total_load, p_min, p_max, out, B);
}